// Round 1
// baseline (214.637 us; speedup 1.0000x reference)
//
#include <hip/hip_runtime.h>

// expm of 3.5M symmetric 3x3 matrices, layout (B=4, 9, 96^3) f32.
// Method: scale 2^-3 + 6-term matrix Taylor (Horner, literal constants only,
// no indexed arrays -> no scratch risk) + 3 squarings. All intermediates are
// polynomials in the same symmetric X -> commute -> symmetric: carry 6 entries.
// Inputs ||S||~<2 -> ||X||<0.25 -> truncation ~1e-8 << 9.6e-2 threshold.
//
// R1 change: stores switched from nontemporal to regular (temporal) stores.
// Theory: NT evict-first policy forces the 127MB write stream to drain toward
// HBM inside the kernel; regular stores let L2/Infinity-Cache absorb the
// writeback (the 256MiB L3 fits the whole output), as the harness fill's
// 6.7 TB/s demonstrates. Loads stay NT (input is read exactly once).

#define N_VOX (96 * 96 * 96) // 884736, divisible by 4*256

typedef float f32x4 __attribute__((ext_vector_type(4)));

struct Sym { float a00, a01, a02, a11, a12, a22; };

// R = X * P  (symmetric because X and P=poly(X) commute)
__device__ __forceinline__ Sym smul(const Sym& x, const Sym& p) {
    Sym r;
    r.a00 = fmaf(x.a00, p.a00, fmaf(x.a01, p.a01, x.a02 * p.a02));
    r.a01 = fmaf(x.a00, p.a01, fmaf(x.a01, p.a11, x.a02 * p.a12));
    r.a02 = fmaf(x.a00, p.a02, fmaf(x.a01, p.a12, x.a02 * p.a22));
    r.a11 = fmaf(x.a01, p.a01, fmaf(x.a11, p.a11, x.a12 * p.a12));
    r.a12 = fmaf(x.a01, p.a02, fmaf(x.a11, p.a12, x.a12 * p.a22));
    r.a22 = fmaf(x.a02, p.a02, fmaf(x.a12, p.a12, x.a22 * p.a22));
    return r;
}

// P <- I + R * c   (Horner step)
__device__ __forceinline__ Sym istep(const Sym& r, float c) {
    Sym p;
    p.a00 = fmaf(r.a00, c, 1.f);
    p.a01 = r.a01 * c;
    p.a02 = r.a02 * c;
    p.a11 = fmaf(r.a11, c, 1.f);
    p.a12 = r.a12 * c;
    p.a22 = fmaf(r.a22, c, 1.f);
    return p;
}

__device__ __forceinline__ Sym ssq(const Sym& p) {
    Sym r;
    r.a00 = fmaf(p.a00, p.a00, fmaf(p.a01, p.a01, p.a02 * p.a02));
    r.a01 = fmaf(p.a00, p.a01, fmaf(p.a01, p.a11, p.a02 * p.a12));
    r.a02 = fmaf(p.a00, p.a02, fmaf(p.a01, p.a12, p.a02 * p.a22));
    r.a11 = fmaf(p.a01, p.a01, fmaf(p.a11, p.a11, p.a12 * p.a12));
    r.a12 = fmaf(p.a01, p.a02, fmaf(p.a11, p.a12, p.a12 * p.a22));
    r.a22 = fmaf(p.a02, p.a02, fmaf(p.a12, p.a12, p.a22 * p.a22));
    return r;
}

__device__ __forceinline__ Sym expm3_sym(Sym x) {
    const float sc = 0.125f; // 2^-3
    x.a00 *= sc; x.a01 *= sc; x.a02 *= sc;
    x.a11 *= sc; x.a12 *= sc; x.a22 *= sc;
    // Horner, 6 terms: P = I + X(I + X/2(I + X/3(I + X/4(I + X/5(I + X/6)))))
    Sym p = istep(x, 1.f / 6.f);
    p = istep(smul(x, p), 0.2f);
    p = istep(smul(x, p), 0.25f);
    p = istep(smul(x, p), 1.f / 3.f);
    p = istep(smul(x, p), 0.5f);
    p = istep(smul(x, p), 1.f);
    // 3 squarings (undo 2^-3 scaling)
    p = ssq(p);
    p = ssq(p);
    p = ssq(p);
    return p;
}

__global__ __launch_bounds__(256) void Expm_54872502174211_kernel(
    const float* __restrict__ x, float* __restrict__ out)
{
    const size_t n = N_VOX;
    const int b = blockIdx.y;
    const int v4 = blockIdx.x * 256 + threadIdx.x; // group of 4 voxels

    const float* base = x + (size_t)b * 9 * n + (size_t)v4 * 4;
    // symmetric matrix channels: 0,1,2,4,5,8 (skip duplicates 3,6,7)
    f32x4 c0 = __builtin_nontemporal_load((const f32x4*)(base + 0 * n));
    f32x4 c1 = __builtin_nontemporal_load((const f32x4*)(base + 1 * n));
    f32x4 c2 = __builtin_nontemporal_load((const f32x4*)(base + 2 * n));
    f32x4 c4 = __builtin_nontemporal_load((const f32x4*)(base + 4 * n));
    f32x4 c5 = __builtin_nontemporal_load((const f32x4*)(base + 5 * n));
    f32x4 c8 = __builtin_nontemporal_load((const f32x4*)(base + 8 * n));

    Sym rx = expm3_sym({c0.x, c1.x, c2.x, c4.x, c5.x, c8.x});
    Sym ry = expm3_sym({c0.y, c1.y, c2.y, c4.y, c5.y, c8.y});
    Sym rz = expm3_sym({c0.z, c1.z, c2.z, c4.z, c5.z, c8.z});
    Sym rw = expm3_sym({c0.w, c1.w, c2.w, c4.w, c5.w, c8.w});

    float* ob = out + (size_t)b * 9 * n + (size_t)v4 * 4;
    f32x4 o0 = {rx.a00, ry.a00, rz.a00, rw.a00};
    f32x4 o1 = {rx.a01, ry.a01, rz.a01, rw.a01};
    f32x4 o2 = {rx.a02, ry.a02, rz.a02, rw.a02};
    f32x4 o4 = {rx.a11, ry.a11, rz.a11, rw.a11};
    f32x4 o5 = {rx.a12, ry.a12, rz.a12, rw.a12};
    f32x4 o8 = {rx.a22, ry.a22, rz.a22, rw.a22};
    // Regular (temporal) stores: let L2/L3 absorb the write stream.
    *(f32x4*)(ob + 0 * n) = o0;
    *(f32x4*)(ob + 1 * n) = o1;
    *(f32x4*)(ob + 2 * n) = o2;
    *(f32x4*)(ob + 3 * n) = o1; // sym dup of 1
    *(f32x4*)(ob + 4 * n) = o4;
    *(f32x4*)(ob + 5 * n) = o5;
    *(f32x4*)(ob + 6 * n) = o2; // dup of 2
    *(f32x4*)(ob + 7 * n) = o5; // dup of 5
    *(f32x4*)(ob + 8 * n) = o8;
}

extern "C" void kernel_launch(void* const* d_in, const int* in_sizes, int n_in,
                              void* d_out, int out_size, void* d_ws, size_t ws_size,
                              hipStream_t stream) {
    const float* x = (const float*)d_in[0];
    float* out = (float*)d_out;
    dim3 grid(N_VOX / (4 * 256), 4); // 864 x 4 blocks, 256 thr, 4 voxels/thr
    Expm_54872502174211_kernel<<<grid, dim3(256), 0, stream>>>(x, out);
}

// Round 2
// 204.273 us; speedup vs baseline: 1.0507x; 1.0507x over previous
//
#include <hip/hip_runtime.h>

// expm of 3.5M symmetric 3x3 matrices, layout (B=4, 9, 96^3) f32.
// Method: scale 2^-3 + 6-term matrix Taylor (Horner, literal constants only,
// no indexed arrays -> no scratch risk) + 3 squarings. All intermediates are
// polynomials in the same symmetric X -> commute -> symmetric: carry 6 entries.
// Inputs ||S||~<2 -> ||X||<0.25 -> truncation ~1e-8 << 9.6e-2 threshold.
//
// R1 post-mortem: temporal stores REGRESSED (+9 us total, kernel ~47->60 us).
//   Kernel-end coherency makes dirty-L2 write streams expensive; NT stores
//   (stream toward HBM during execution) restored here.
// R2 change: 2 voxels/thread (was 4). Doubles wave count (27648 waves,
//   27 blocks/CU vs 13.5 non-integral), halves each wave's serial compute
//   chain, doubles the number of independent load/store phases in flight.
//   Theory: kernel is latency/phase-limited, not BW-limited (4.5 TB/s vs
//   ~6 achievable). dwordx2 = 8B/lane, still fully coalesced.

#define N_VOX (96 * 96 * 96) // 884736, divisible by 2*256

typedef float f32x2 __attribute__((ext_vector_type(2)));

struct Sym { float a00, a01, a02, a11, a12, a22; };

// R = X * P  (symmetric because X and P=poly(X) commute)
__device__ __forceinline__ Sym smul(const Sym& x, const Sym& p) {
    Sym r;
    r.a00 = fmaf(x.a00, p.a00, fmaf(x.a01, p.a01, x.a02 * p.a02));
    r.a01 = fmaf(x.a00, p.a01, fmaf(x.a01, p.a11, x.a02 * p.a12));
    r.a02 = fmaf(x.a00, p.a02, fmaf(x.a01, p.a12, x.a02 * p.a22));
    r.a11 = fmaf(x.a01, p.a01, fmaf(x.a11, p.a11, x.a12 * p.a12));
    r.a12 = fmaf(x.a01, p.a02, fmaf(x.a11, p.a12, x.a12 * p.a22));
    r.a22 = fmaf(x.a02, p.a02, fmaf(x.a12, p.a12, x.a22 * p.a22));
    return r;
}

// P <- I + R * c   (Horner step)
__device__ __forceinline__ Sym istep(const Sym& r, float c) {
    Sym p;
    p.a00 = fmaf(r.a00, c, 1.f);
    p.a01 = r.a01 * c;
    p.a02 = r.a02 * c;
    p.a11 = fmaf(r.a11, c, 1.f);
    p.a12 = r.a12 * c;
    p.a22 = fmaf(r.a22, c, 1.f);
    return p;
}

__device__ __forceinline__ Sym ssq(const Sym& p) {
    Sym r;
    r.a00 = fmaf(p.a00, p.a00, fmaf(p.a01, p.a01, p.a02 * p.a02));
    r.a01 = fmaf(p.a00, p.a01, fmaf(p.a01, p.a11, p.a02 * p.a12));
    r.a02 = fmaf(p.a00, p.a02, fmaf(p.a01, p.a12, p.a02 * p.a22));
    r.a11 = fmaf(p.a01, p.a01, fmaf(p.a11, p.a11, p.a12 * p.a12));
    r.a12 = fmaf(p.a01, p.a02, fmaf(p.a11, p.a12, p.a12 * p.a22));
    r.a22 = fmaf(p.a02, p.a02, fmaf(p.a12, p.a12, p.a22 * p.a22));
    return r;
}

__device__ __forceinline__ Sym expm3_sym(Sym x) {
    const float sc = 0.125f; // 2^-3
    x.a00 *= sc; x.a01 *= sc; x.a02 *= sc;
    x.a11 *= sc; x.a12 *= sc; x.a22 *= sc;
    // Horner, 6 terms: P = I + X(I + X/2(I + X/3(I + X/4(I + X/5(I + X/6)))))
    Sym p = istep(x, 1.f / 6.f);
    p = istep(smul(x, p), 0.2f);
    p = istep(smul(x, p), 0.25f);
    p = istep(smul(x, p), 1.f / 3.f);
    p = istep(smul(x, p), 0.5f);
    p = istep(smul(x, p), 1.f);
    // 3 squarings (undo 2^-3 scaling)
    p = ssq(p);
    p = ssq(p);
    p = ssq(p);
    return p;
}

__global__ __launch_bounds__(256) void Expm_54872502174211_kernel(
    const float* __restrict__ x, float* __restrict__ out)
{
    const size_t n = N_VOX;
    const int b = blockIdx.y;
    const int v2 = blockIdx.x * 256 + threadIdx.x; // group of 2 voxels

    const float* base = x + (size_t)b * 9 * n + (size_t)v2 * 2;
    // symmetric matrix channels: 0,1,2,4,5,8 (skip duplicates 3,6,7)
    f32x2 c0 = __builtin_nontemporal_load((const f32x2*)(base + 0 * n));
    f32x2 c1 = __builtin_nontemporal_load((const f32x2*)(base + 1 * n));
    f32x2 c2 = __builtin_nontemporal_load((const f32x2*)(base + 2 * n));
    f32x2 c4 = __builtin_nontemporal_load((const f32x2*)(base + 4 * n));
    f32x2 c5 = __builtin_nontemporal_load((const f32x2*)(base + 5 * n));
    f32x2 c8 = __builtin_nontemporal_load((const f32x2*)(base + 8 * n));

    Sym rx = expm3_sym({c0.x, c1.x, c2.x, c4.x, c5.x, c8.x});
    Sym ry = expm3_sym({c0.y, c1.y, c2.y, c4.y, c5.y, c8.y});

    float* ob = out + (size_t)b * 9 * n + (size_t)v2 * 2;
    f32x2 o0 = {rx.a00, ry.a00};
    f32x2 o1 = {rx.a01, ry.a01};
    f32x2 o2 = {rx.a02, ry.a02};
    f32x2 o4 = {rx.a11, ry.a11};
    f32x2 o5 = {rx.a12, ry.a12};
    f32x2 o8 = {rx.a22, ry.a22};
    __builtin_nontemporal_store(o0, (f32x2*)(ob + 0 * n));
    __builtin_nontemporal_store(o1, (f32x2*)(ob + 1 * n));
    __builtin_nontemporal_store(o2, (f32x2*)(ob + 2 * n));
    __builtin_nontemporal_store(o1, (f32x2*)(ob + 3 * n)); // sym dup of 1
    __builtin_nontemporal_store(o4, (f32x2*)(ob + 4 * n));
    __builtin_nontemporal_store(o5, (f32x2*)(ob + 5 * n));
    __builtin_nontemporal_store(o2, (f32x2*)(ob + 6 * n)); // dup of 2
    __builtin_nontemporal_store(o5, (f32x2*)(ob + 7 * n)); // dup of 5
    __builtin_nontemporal_store(o8, (f32x2*)(ob + 8 * n));
}

extern "C" void kernel_launch(void* const* d_in, const int* in_sizes, int n_in,
                              void* d_out, int out_size, void* d_ws, size_t ws_size,
                              hipStream_t stream) {
    const float* x = (const float*)d_in[0];
    float* out = (float*)d_out;
    dim3 grid(N_VOX / (2 * 256), 4); // 1728 x 4 blocks, 256 thr, 2 voxels/thr
    Expm_54872502174211_kernel<<<grid, dim3(256), 0, stream>>>(x, out);
}